// Round 9
// baseline (102.115 us; speedup 1.0000x reference)
//
#include <hip/hip_runtime.h>

typedef __attribute__((ext_vector_type(8))) short short8;
typedef __attribute__((ext_vector_type(8))) unsigned short ushort8;
typedef __attribute__((ext_vector_type(4))) float f32x4;

// Problem constants
constexpr int B_ = 8, IN_C_ = 64, IN_L_ = 64, T_ = 256, OUT_C_ = 64, OUT_L_ = 64;
constexpr float EPS_ = 1e-5f;

// xT_pad: bf16 [8 b][66 lp][258 tp][64 ic]; lp = l+1, tp = t+1, halo rows/cols = 0
constexpr int XT_LP = 66, XT_TP = 258, XT_IC = 64;
constexpr int XT_LSTRIDE = XT_TP * XT_IC;            // 16512 elems
constexpr int XT_BSTRIDE = XT_LP * XT_LSTRIDE;       // 1,089,792 elems
constexpr size_t XT_ELEMS = (size_t)B_ * XT_BSTRIDE; // 8,718,336
constexpr size_t XT_BYTES = XT_ELEMS * 2;            // 17,436,672
// wT2: bf16 [64 l][9 tap][64 c][64 ic]
constexpr size_t WT2_ELEMS = 64ull * 9 * 64 * 64;    // 2,359,296
constexpr size_t WT2_OFF_B = XT_BYTES;
constexpr size_t PART_OFF_B = WT2_OFF_B + WT2_ELEMS * 2;    // 22,155,264
constexpr size_t SS_OFF_B = PART_OFF_B + 1024ull * 128 * 4; // 22,679,552
constexpr size_t WS_NEED = SS_OFF_B + 128 * 4;              // 22,680,064
// optional bf16 intermediate (pre-BN conv output), 16.78 MB
constexpr size_t TMP_OFF_B = WS_NEED;
constexpr size_t TMP_BYTES = (size_t)B_ * OUT_C_ * OUT_L_ * T_ * 2;
constexpr size_t WS_NEED2 = TMP_OFF_B + TMP_BYTES;          // 39,457,280

__device__ __forceinline__ unsigned short f2bf(float f) {
  unsigned u = __float_as_uint(f);
  return (unsigned short)((u + 0x7fffu + ((u >> 16) & 1u)) >> 16);
}

__device__ __forceinline__ void gload_lds16(const void* g, void* l) {
  __builtin_amdgcn_global_load_lds(
      (const __attribute__((address_space(1))) unsigned int*)g,
      (__attribute__((address_space(3))) unsigned int*)l, 16, 0, 0);
}

// ---------------------------------------------------------------------------
// Prep: blocks [0,1024): x fp32 [b][ic][l][t] -> xT bf16 [b][l+1][t+1][ic]
// (LDS transpose). Blocks [1024,1168): w -> wT2 bf16 [l][tap][c][ic].
// Blocks [1168,1176): zero xT halo (663 KB).
// ---------------------------------------------------------------------------
__global__ __launch_bounds__(256) void prep_kernel(const float* __restrict__ x,
                                                   const float* __restrict__ w,
                                                   unsigned short* __restrict__ xT,
                                                   unsigned short* __restrict__ wT2) {
  const int bid = blockIdx.x;
  const int tid = threadIdx.x;
  if (bid < 1024) {
    const int th = bid & 1, l = (bid >> 1) & 63, b = bid >> 7;
    const int t0 = th * 128;
    __shared__ unsigned short ls[64][132];  // [ic][t-local], pad keeps rows 8B-aligned
    {
      const int ic = tid >> 2, q = tid & 3;
      const float4* src = (const float4*)(x + (((size_t)(b * 64 + ic) * 64 + l) * 256 + t0));
#pragma unroll
      for (int e = 0; e < 8; ++e) {
        float4 v = src[q * 8 + e];
        const int toff = (q * 8 + e) * 4;
        unsigned d0 = f2bf(v.x) | ((unsigned)f2bf(v.y) << 16);
        unsigned d1 = f2bf(v.z) | ((unsigned)f2bf(v.w) << 16);
        *(uint2*)&ls[ic][toff] = make_uint2(d0, d1);
      }
    }
    __syncthreads();
    {
      const int tl = tid >> 1, h = tid & 1;  // t-row, ic-half
      unsigned d[16];
#pragma unroll
      for (int k = 0; k < 16; ++k) {
        unsigned short a = ls[h * 32 + 2 * k][tl];
        unsigned short c = ls[h * 32 + 2 * k + 1][tl];
        d[k] = a | ((unsigned)c << 16);
      }
      unsigned short* dst =
          xT + ((size_t)(b * XT_LP + l + 1) * XT_TP + (t0 + tl + 1)) * XT_IC + h * 32;
      uint4* dv = (uint4*)dst;
      dv[0] = make_uint4(d[0], d[1], d[2], d[3]);
      dv[1] = make_uint4(d[4], d[5], d[6], d[7]);
      dv[2] = make_uint4(d[8], d[9], d[10], d[11]);
      dv[3] = make_uint4(d[12], d[13], d[14], d[15]);
    }
  } else if (bid < 1168) {
    const int g = (bid - 1024) * 256 + tid;  // 0..36863
    const int c = g & 63;
    const int lt = g >> 6;  // l*9 + tap
    const int l = lt / 9;
    const int tap = lt % 9;
    unsigned short* dst = wT2 + ((size_t)lt * 64 + c) * 64;
    const float* src = w + ((size_t)tap * 64 + c) * 64 + l;  // + ic*9*4096
#pragma unroll
    for (int ic0 = 0; ic0 < 64; ic0 += 8) {
      unsigned d[4];
#pragma unroll
      for (int k = 0; k < 4; ++k) {
        float a = src[(size_t)(ic0 + 2 * k) * 9 * 4096];
        float c2 = src[(size_t)(ic0 + 2 * k + 1) * 9 * 4096];
        d[k] = f2bf(a) | ((unsigned)f2bf(c2) << 16);
      }
      *(uint4*)(dst + ic0) = make_uint4(d[0], d[1], d[2], d[3]);
    }
  } else {
    const int b = bid - 1168;  // 0..7
    unsigned short* base = xT + (size_t)b * XT_BSTRIDE;
    const short8 z = {};
    for (int ci = tid; ci < 5184; ci += 256) {
      size_t off;
      if (ci < 4128) {
        const int plane = ci / 2064, k = ci % 2064;
        off = (size_t)(plane ? 65 : 0) * XT_LSTRIDE + (size_t)k * 8;
      } else {
        const int k = ci - 4128;
        const int lp = k >> 4, rem = k & 15;
        const int tp = (rem < 8) ? 0 : 257;
        off = ((size_t)lp * XT_TP + tp) * 64 + (size_t)(rem & 7) * 8;
      }
      *(short8*)(base + off) = z;
    }
  }
}

// ---------------------------------------------------------------------------
// Main conv (stage-once): block = (b, l, th) -> 1024 blocks x 128 threads
// (2 waves, each 64t x 64c, acc 4x4). A = 3 contiguous xT rows x 130-t window
// (48.75 KB) staged ONCE via global_load_lds with pre-swizzled source; all 9
// taps then read A at LDS offsets (i*130 + m + j). B = wT2[l][tap] (8 KB)
// single-buffered with register prefetch (load tap+1 -> regs before compute,
// ds_write after barrier; all waitcnts compiler-automatic).
// Epilogue: bias, bf16/fp32 store, fused per-channel sum/sumsq partials.
// ---------------------------------------------------------------------------
__global__ __launch_bounds__(128) void conv_mfma(
    const unsigned short* __restrict__ xT, const unsigned short* __restrict__ wT2,
    const float* __restrict__ bias, float* __restrict__ outf,
    unsigned short* __restrict__ tmpb, float* __restrict__ part) {
  const int orig = blockIdx.x;                    // 0..1023
  const int wg = (orig & 7) * 128 + (orig >> 3);  // XCD x -> batch b = x
  const int b = wg >> 7;
  const int l = (wg >> 1) & 63;
  const int th = wg & 1;
  const int tid = threadIdx.x;                    // 0..127
  const int wid = tid >> 6, ln = tid & 63;
  const int lc = ln & 15, lg = ln >> 4;
  const int tp0 = th * 128;

  // A: 3*130*64 = 24960 elems (49,920 B) | B: 4096 elems (8,192 B)
  __shared__ unsigned short lds[24960 + 4096];
  unsigned short* Al = &lds[0];
  unsigned short* Bl = &lds[24960];

  // ---- A-stage: 3120 16B chunks, once. chunk ci -> (i, tloc, slot).
  // Pre-swizzled source (m173): dst slot s of row tloc holds global slot
  // s ^ (tloc & 7). Wave-uniform LDS base + per-lane global address.
  {
    const size_t rowbase = ((size_t)(b * XT_LP + l) * XT_TP + tp0) * 64;
#pragma unroll
    for (int k = 0; k < 25; ++k) {
      const int cbase = k * 128 + wid * 64;  // wave-uniform chunk base
      const int ci = cbase + ln;
      if (ci < 3120) {
        const int i = ci / 1040;
        const int r = ci - i * 1040;
        const int tloc = r >> 3, slot = r & 7;
        const unsigned short* src =
            xT + rowbase + (size_t)i * XT_LSTRIDE + tloc * 64 + ((slot ^ (tloc & 7)) << 3);
        gload_lds16(src, Al + (size_t)cbase * 8);
      }
    }
  }

  // ---- B prefetch helpers (register-staged, swizzled like A)
  const unsigned short* wBase = wT2 + (size_t)l * 9 * 4096;
  uint4 bpre[4];
  auto BLOAD = [&](int tap) {
#pragma unroll
    for (int q = 0; q < 4; ++q) {
      const int cb = tid + q * 128;
      const int c = cb >> 3, sl = cb & 7;
      bpre[q] = *(const uint4*)(wBase + (size_t)tap * 4096 + c * 64 + ((sl ^ (c & 7)) << 3));
    }
  };
  auto BWRITE = [&]() {
#pragma unroll
    for (int q = 0; q < 4; ++q) *(uint4*)(Bl + (size_t)(tid + q * 128) * 8) = bpre[q];
  };

  f32x4 acc[4][4] = {};

  BLOAD(0);
  BWRITE();        // compiler waits vmcnt for bpre deps
  __syncthreads(); // drains A-stage vmem + B ds_writes (compiler-inserted waits)

#pragma unroll
  for (int tap = 0; tap < 9; ++tap) {
    if (tap + 1 < 9) BLOAD(tap + 1);  // in-flight during compute
    const int i = tap / 3, j = tap - i * 3;
#pragma unroll
    for (int kb = 0; kb < 2; ++kb) {
      short8 af[4], bf[4];
#pragma unroll
      for (int mi = 0; mi < 4; ++mi) {
        const int tloc = wid * 64 + mi * 16 + lc + j;
        af[mi] = *(const short8*)(Al + (i * 130 + tloc) * 64 +
                                  (((kb * 4 + lg) ^ (tloc & 7)) << 3));
      }
#pragma unroll
      for (int ni = 0; ni < 4; ++ni)
        bf[ni] = *(const short8*)(Bl + (ni * 16 + lc) * 64 +
                                  (((kb * 4 + lg) ^ (lc & 7)) << 3));
#pragma unroll
      for (int mi = 0; mi < 4; ++mi)
#pragma unroll
        for (int ni = 0; ni < 4; ++ni)
          acc[mi][ni] =
              __builtin_amdgcn_mfma_f32_16x16x32_bf16(af[mi], bf[ni], acc[mi][ni], 0, 0, 0);
    }
    __syncthreads();                      // all waves done reading Bl
    if (tap + 1 < 9) {
      BWRITE();                           // regs arrived long ago (auto vmcnt)
      __syncthreads();                    // Bl(tap+1) visible (auto lgkmcnt)
    }
  }

  // ---- epilogue: bias + store + fused stats.
  // D: t = tp0 + wid*64 + mi*16 + lg*4 + r, c = ni*16 + lc
  float* sm = (float*)&lds[0];  // reuse A area: sm[(wid*4+ni)*32 + lc*2 + sel]
#pragma unroll
  for (int ni = 0; ni < 4; ++ni) {
    const int c = ni * 16 + lc;
    const float bv = bias[c * 64 + l];
    float s = 0.f, s2 = 0.f;
    const size_t obase = ((size_t)(b * 64 + c) * 64 + l) * 256 + tp0 + wid * 64;
#pragma unroll
    for (int mi = 0; mi < 4; ++mi) {
      float vv[4];
#pragma unroll
      for (int r = 0; r < 4; ++r) {
        float v = acc[mi][ni][r] + bv;
        vv[r] = v;
        s += v;
        s2 += v * v;
      }
      if (tmpb) {
        unsigned d0 = f2bf(vv[0]) | ((unsigned)f2bf(vv[1]) << 16);
        unsigned d1 = f2bf(vv[2]) | ((unsigned)f2bf(vv[3]) << 16);
        *(uint2*)(tmpb + obase + mi * 16 + lg * 4) = make_uint2(d0, d1);
      } else {
        *(float4*)(outf + obase + mi * 16 + lg * 4) =
            make_float4(vv[0], vv[1], vv[2], vv[3]);
      }
    }
    s += __shfl_xor(s, 16);  s += __shfl_xor(s, 32);
    s2 += __shfl_xor(s2, 16); s2 += __shfl_xor(s2, 32);
    if (lg == 0) {
      sm[(wid * 4 + ni) * 32 + lc * 2] = s;
      sm[(wid * 4 + ni) * 32 + lc * 2 + 1] = s2;
    }
  }
  __syncthreads();
  {
    const int sel = tid >> 6, cc = tid & 63;  // 128 threads cover sel 0,1 x 64 c
    const int ni = cc >> 4, lc2 = cc & 15;
    float r = sm[(0 * 4 + ni) * 32 + lc2 * 2 + sel] + sm[(1 * 4 + ni) * 32 + lc2 * 2 + sel];
    part[(size_t)wg * 128 + sel * 64 + cc] = r;
  }
}

// ---------------------------------------------------------------------------
// Finalize per-channel scale/shift from 1024 block-partials.
// ---------------------------------------------------------------------------
__global__ __launch_bounds__(256) void stats_final_mf(
    const float* __restrict__ part, const float* __restrict__ gamma,
    const float* __restrict__ beta, float* __restrict__ ss) {
  const int c = blockIdx.x;  // 0..63
  const int tid = threadIdx.x;
  float s = 0.f, s2 = 0.f;
  for (int blk = tid; blk < 1024; blk += 256) {
    s += part[(size_t)blk * 128 + c];
    s2 += part[(size_t)blk * 128 + 64 + c];
  }
#pragma unroll
  for (int off = 32; off; off >>= 1) {
    s += __shfl_down(s, off);
    s2 += __shfl_down(s2, off);
  }
  __shared__ float r0[4], r1[4];
  const int wid = tid >> 6, lane = tid & 63;
  if (lane == 0) { r0[wid] = s; r1[wid] = s2; }
  __syncthreads();
  if (tid == 0) {
    float S = r0[0] + r0[1] + r0[2] + r0[3];
    float S2 = r1[0] + r1[1] + r1[2] + r1[3];
    const float inv_n = 1.0f / 131072.f;
    float mean = S * inv_n;
    float var = S2 * inv_n - mean * mean;
    float inv = rsqrtf(var + EPS_);
    float sc = gamma[c] * inv;
    ss[c] = sc;
    ss[64 + c] = beta[c] - mean * sc;
  }
}

// ---------------------------------------------------------------------------
// BN apply + PReLU reading bf16 intermediate, writing fp32 out.
// ---------------------------------------------------------------------------
__global__ __launch_bounds__(256) void bn_prelu_b(
    const unsigned short* __restrict__ tmp, const float* __restrict__ ss,
    const float* __restrict__ alpha, float* __restrict__ out) {
  const float a = alpha[0];
  constexpr size_t N8 = (size_t)B_ * OUT_C_ * OUT_L_ * T_ / 8;  // 1,048,576
  for (size_t i = (size_t)blockIdx.x * 256 + threadIdx.x; i < N8;
       i += (size_t)gridDim.x * 256) {
    const int c = (int)((i >> 11) & 63);  // 2048 8-elem chunks per channel
    const float sc = ss[c];
    const float sh = ss[64 + c];
    ushort8 v = *(const ushort8*)(tmp + i * 8);
    float o[8];
#pragma unroll
    for (int r = 0; r < 8; ++r) {
      float f = __uint_as_float(((unsigned)v[r]) << 16) * sc + sh;
      o[r] = (f >= 0.f) ? f : a * f;
    }
    float4* op = (float4*)(out + i * 8);
    op[0] = make_float4(o[0], o[1], o[2], o[3]);
    op[1] = make_float4(o[4], o[5], o[6], o[7]);
  }
}

// ---------------------------------------------------------------------------
// BN apply + PReLU, fp32 in place (fallback when ws too small for tmp).
// ---------------------------------------------------------------------------
__global__ __launch_bounds__(256) void bn_prelu(
    float* __restrict__ out, const float* __restrict__ scaleshift,
    const float* __restrict__ alpha) {
  const float a = alpha[0];
  constexpr size_t N4 = (size_t)B_ * OUT_C_ * OUT_L_ * T_ / 4;
  float4* p = (float4*)out;
  for (size_t i = (size_t)blockIdx.x * 256 + threadIdx.x; i < N4;
       i += (size_t)gridDim.x * 256) {
    const int c = (int)((i >> 12) & 63);
    const float sc = scaleshift[c];
    const float sh = scaleshift[64 + c];
    float4 v = p[i];
    v.x = v.x * sc + sh; v.x = (v.x >= 0.f) ? v.x : a * v.x;
    v.y = v.y * sc + sh; v.y = (v.y >= 0.f) ? v.y : a * v.y;
    v.z = v.z * sc + sh; v.z = (v.z >= 0.f) ? v.z : a * v.z;
    v.w = v.w * sc + sh; v.w = (v.w >= 0.f) ? v.w : a * v.w;
    p[i] = v;
  }
}

extern "C" void kernel_launch(void* const* d_in, const int* in_sizes, int n_in,
                              void* d_out, int out_size, void* d_ws, size_t ws_size,
                              hipStream_t stream) {
  const float* x = (const float*)d_in[0];
  const float* w = (const float*)d_in[1];
  const float* bias = (const float*)d_in[2];
  const float* gamma = (const float*)d_in[3];
  const float* beta = (const float*)d_in[4];
  const float* alpha = (const float*)d_in[5];
  float* out = (float*)d_out;

  unsigned short* xT = (unsigned short*)d_ws;
  unsigned short* wT2 = (unsigned short*)((char*)d_ws + WT2_OFF_B);
  float* part = (float*)((char*)d_ws + PART_OFF_B);
  float* ssb = (float*)((char*)d_ws + SS_OFF_B);

  if (ws_size >= WS_NEED2) {
    unsigned short* tmpb = (unsigned short*)((char*)d_ws + TMP_OFF_B);
    prep_kernel<<<dim3(1176), dim3(256), 0, stream>>>(x, w, xT, wT2);
    conv_mfma<<<dim3(1024), dim3(128), 0, stream>>>(xT, wT2, bias, out, tmpb, part);
    stats_final_mf<<<dim3(64), dim3(256), 0, stream>>>(part, gamma, beta, ssb);
    bn_prelu_b<<<dim3(2048), dim3(256), 0, stream>>>(tmpb, ssb, alpha, out);
  } else if (ws_size >= WS_NEED) {
    prep_kernel<<<dim3(1176), dim3(256), 0, stream>>>(x, w, xT, wT2);
    conv_mfma<<<dim3(1024), dim3(128), 0, stream>>>(xT, wT2, bias, out, nullptr, part);
    stats_final_mf<<<dim3(64), dim3(256), 0, stream>>>(part, gamma, beta, ssb);
    bn_prelu<<<dim3(2048), dim3(256), 0, stream>>>(out, ssb, alpha);
  }
}

// Round 10
// 84.051 us; speedup vs baseline: 1.2149x; 1.2149x over previous
//
#include <hip/hip_runtime.h>

typedef __attribute__((ext_vector_type(8))) short short8;
typedef __attribute__((ext_vector_type(8))) unsigned short ushort8;
typedef __attribute__((ext_vector_type(4))) float f32x4;

// Problem constants
constexpr int B_ = 8, IN_C_ = 64, IN_L_ = 64, T_ = 256, OUT_C_ = 64, OUT_L_ = 64;
constexpr float EPS_ = 1e-5f;

// xT_pad: bf16 [8 b][66 lp][258 tp][64 ic]; lp = l+1, tp = t+1, halo rows/cols = 0
constexpr int XT_LP = 66, XT_TP = 258, XT_IC = 64;
constexpr int XT_LSTRIDE = XT_TP * XT_IC;            // 16512 elems
constexpr int XT_BSTRIDE = XT_LP * XT_LSTRIDE;       // 1,089,792 elems
constexpr size_t XT_ELEMS = (size_t)B_ * XT_BSTRIDE; // 8,718,336
constexpr size_t XT_BYTES = XT_ELEMS * 2;            // 17,436,672
// wT2: bf16 [64 l][9 tap][64 c][64 ic]
constexpr size_t WT2_ELEMS = 64ull * 9 * 64 * 64;    // 2,359,296
constexpr size_t WT2_OFF_B = XT_BYTES;
constexpr size_t PART_OFF_B = WT2_OFF_B + WT2_ELEMS * 2;    // 22,155,264
constexpr size_t SS_OFF_B = PART_OFF_B + 1024ull * 128 * 4; // 22,679,552
constexpr size_t WS_NEED = SS_OFF_B + 128 * 4;              // 22,680,064
// bf16 intermediate (pre-BN conv output), 16.78 MB
constexpr size_t TMP_OFF_B = WS_NEED;
constexpr size_t TMP_BYTES = (size_t)B_ * OUT_C_ * OUT_L_ * T_ * 2;
constexpr size_t WS_NEED2 = TMP_OFF_B + TMP_BYTES;          // 39,457,280

__device__ __forceinline__ unsigned short f2bf(float f) {
  unsigned u = __float_as_uint(f);
  return (unsigned short)((u + 0x7fffu + ((u >> 16) & 1u)) >> 16);
}

__device__ __forceinline__ void gload_lds16(const void* g, void* l) {
  __builtin_amdgcn_global_load_lds(
      (const __attribute__((address_space(1))) unsigned int*)g,
      (__attribute__((address_space(3))) unsigned int*)l, 16, 0, 0);
}

// ---------------------------------------------------------------------------
// Prep: blocks [0,1024): x fp32 [b][ic][l][t] -> xT bf16 [b][l+1][t+1][ic]
// (LDS transpose). Blocks [1024,1168): w -> wT2 bf16 [l][tap][c][ic].
// Blocks [1168,1176): zero xT halo (663 KB).
// ---------------------------------------------------------------------------
__global__ __launch_bounds__(256) void prep_kernel(const float* __restrict__ x,
                                                   const float* __restrict__ w,
                                                   unsigned short* __restrict__ xT,
                                                   unsigned short* __restrict__ wT2) {
  const int bid = blockIdx.x;
  const int tid = threadIdx.x;
  if (bid < 1024) {
    const int th = bid & 1, l = (bid >> 1) & 63, b = bid >> 7;
    const int t0 = th * 128;
    __shared__ unsigned short ls[64][132];  // [ic][t-local], pad keeps rows 8B-aligned
    {
      const int ic = tid >> 2, q = tid & 3;
      const float4* src = (const float4*)(x + (((size_t)(b * 64 + ic) * 64 + l) * 256 + t0));
#pragma unroll
      for (int e = 0; e < 8; ++e) {
        float4 v = src[q * 8 + e];
        const int toff = (q * 8 + e) * 4;
        unsigned d0 = f2bf(v.x) | ((unsigned)f2bf(v.y) << 16);
        unsigned d1 = f2bf(v.z) | ((unsigned)f2bf(v.w) << 16);
        *(uint2*)&ls[ic][toff] = make_uint2(d0, d1);
      }
    }
    __syncthreads();
    {
      const int tl = tid >> 1, h = tid & 1;  // t-row, ic-half
      unsigned d[16];
#pragma unroll
      for (int k = 0; k < 16; ++k) {
        unsigned short a = ls[h * 32 + 2 * k][tl];
        unsigned short c = ls[h * 32 + 2 * k + 1][tl];
        d[k] = a | ((unsigned)c << 16);
      }
      unsigned short* dst =
          xT + ((size_t)(b * XT_LP + l + 1) * XT_TP + (t0 + tl + 1)) * XT_IC + h * 32;
      uint4* dv = (uint4*)dst;
      dv[0] = make_uint4(d[0], d[1], d[2], d[3]);
      dv[1] = make_uint4(d[4], d[5], d[6], d[7]);
      dv[2] = make_uint4(d[8], d[9], d[10], d[11]);
      dv[3] = make_uint4(d[12], d[13], d[14], d[15]);
    }
  } else if (bid < 1168) {
    const int g = (bid - 1024) * 256 + tid;  // 0..36863
    const int c = g & 63;
    const int lt = g >> 6;  // l*9 + tap
    const int l = lt / 9;
    const int tap = lt % 9;
    unsigned short* dst = wT2 + ((size_t)lt * 64 + c) * 64;
    const float* src = w + ((size_t)tap * 64 + c) * 64 + l;  // + ic*9*4096
#pragma unroll
    for (int ic0 = 0; ic0 < 64; ic0 += 8) {
      unsigned d[4];
#pragma unroll
      for (int k = 0; k < 4; ++k) {
        float a = src[(size_t)(ic0 + 2 * k) * 9 * 4096];
        float c2 = src[(size_t)(ic0 + 2 * k + 1) * 9 * 4096];
        d[k] = f2bf(a) | ((unsigned)f2bf(c2) << 16);
      }
      *(uint4*)(dst + ic0) = make_uint4(d[0], d[1], d[2], d[3]);
    }
  } else {
    const int b = bid - 1168;  // 0..7
    unsigned short* base = xT + (size_t)b * XT_BSTRIDE;
    const short8 z = {};
    for (int ci = tid; ci < 5184; ci += 256) {
      size_t off;
      if (ci < 4128) {
        const int plane = ci / 2064, k = ci % 2064;
        off = (size_t)(plane ? 65 : 0) * XT_LSTRIDE + (size_t)k * 8;
      } else {
        const int k = ci - 4128;
        const int lp = k >> 4, rem = k & 15;
        const int tp = (rem < 8) ? 0 : 257;
        off = ((size_t)lp * XT_TP + tp) * 64 + (size_t)(rem & 7) * 8;
      }
      *(short8*)(base + off) = z;
    }
  }
}

// ---------------------------------------------------------------------------
// Main conv v3 (row-staged): block = (b,l), 256 threads (4 waves, each
// 64t x 64c, acc 4x4). A = one xT row (258 tp x 64 ic, 33 KB) staged per
// i-row via global_load_lds with pre-swizzled source (m173); 3 stages, each
// serving 3 taps (2 barriers per stage). B is NEVER staged: per tap, each
// wave loads its 8 B-fragments straight from L2-resident wT2 into registers
// with 1-tap lookahead (ping-pong arrays, fully unrolled -> static indexing).
// Epilogue: bias, bf16/fp32 store, fused per-channel sum/sumsq partials.
// ---------------------------------------------------------------------------
__global__ __launch_bounds__(256, 3) void conv_mfma(
    const unsigned short* __restrict__ xT, const unsigned short* __restrict__ wT2,
    const float* __restrict__ bias, float* __restrict__ outf,
    unsigned short* __restrict__ tmpb, float* __restrict__ part) {
  const int orig = blockIdx.x;                   // 0..511
  const int wg = (orig & 7) * 64 + (orig >> 3);  // XCD x -> batch b = x (L2 locality)
  const int b = wg >> 6, l = wg & 63;
  const int tid = threadIdx.x;
  const int wid = tid >> 6, ln = tid & 63;
  const int lc = ln & 15, lg = ln >> 4;
  const int m0 = wid * 64;

  __shared__ unsigned short Arow[XT_TP * 64];  // 33,024 B (also reused as sm)

  const size_t xrowbase = (size_t)(b * XT_LP + l) * XT_LSTRIDE;
  // per-lane B base: c = ni*16+lc, ic-slot = kb*4+lg
  const unsigned short* wBase = wT2 + (size_t)l * 9 * 4096 + lc * 64 + lg * 8;

  // Stage xT row (l+i) into Arow, XOR-swizzled: LDS slot s of row tp holds
  // global slot s^(tp&7). 2064 16B chunks; wave-uniform LDS base + lane*16.
  auto ASTAGE = [&](int i) {
    const unsigned short* rb = xT + xrowbase + (size_t)i * XT_LSTRIDE;
#pragma unroll
    for (int k = 0; k < 9; ++k) {
      const int cbase = k * 256 + wid * 64;  // wave-uniform
      const int ci = cbase + ln;
      if (ci < 2064) {
        const int tp = ci >> 3, sl = ci & 7;
        gload_lds16(rb + tp * 64 + ((sl ^ (tp & 7)) << 3), Arow + (size_t)cbase * 8);
      }
    }
  };
  auto BLOAD = [&](int tap, short8* dst) {
#pragma unroll
    for (int kb = 0; kb < 2; ++kb)
#pragma unroll
      for (int ni = 0; ni < 4; ++ni)
        dst[kb * 4 + ni] =
            *(const short8*)(wBase + (size_t)tap * 4096 + ni * 1024 + kb * 32);
  };

  f32x4 acc[4][4] = {};
  short8 bA[8], bB[8];

  ASTAGE(0);
  BLOAD(0, bA);
  __syncthreads();  // drains A-stage (vmcnt) + barrier: row 0 + bA ready

#pragma unroll
  for (int i = 0; i < 3; ++i) {
#pragma unroll
    for (int j = 0; j < 3; ++j) {
      const int tap = i * 3 + j;                    // compile-time (unrolled)
      short8* bc = ((tap & 1) == 0) ? bA : bB;
      short8* bn = ((tap & 1) == 0) ? bB : bA;
      if (tap + 1 < 9) BLOAD(tap + 1, bn);          // in flight under MFMAs
#pragma unroll
      for (int kb = 0; kb < 2; ++kb) {
        short8 af[4];
#pragma unroll
        for (int mi = 0; mi < 4; ++mi) {
          const int tp = m0 + mi * 16 + lc + j;     // tp = t + j
          af[mi] = *(const short8*)(Arow + tp * 64 + (((kb * 4 + lg) ^ (tp & 7)) << 3));
        }
#pragma unroll
        for (int mi = 0; mi < 4; ++mi)
#pragma unroll
          for (int ni = 0; ni < 4; ++ni)
            acc[mi][ni] = __builtin_amdgcn_mfma_f32_16x16x32_bf16(
                af[mi], bc[kb * 4 + ni], acc[mi][ni], 0, 0, 0);
      }
    }
    if (i + 1 < 3) {
      __syncthreads();   // all waves done reading Arow(i)
      ASTAGE(i + 1);
      __syncthreads();   // implicit vmcnt(0): row i+1 landed & visible
    }
  }

  // ---- epilogue: bias + store + fused stats.
  // D: t = m0 + mi*16 + lg*4 + r, c = ni*16 + lc
  __syncthreads();
  float* sm = (float*)&Arow[0];  // sm[(wid*4+ni)*32 + lc*2 + sel]
#pragma unroll
  for (int ni = 0; ni < 4; ++ni) {
    const int c = ni * 16 + lc;
    const float bv = bias[c * 64 + l];
    float s = 0.f, s2 = 0.f;
    const size_t obase = ((size_t)(b * 64 + c) * 64 + l) * 256 + m0;
#pragma unroll
    for (int mi = 0; mi < 4; ++mi) {
      float vv[4];
#pragma unroll
      for (int r = 0; r < 4; ++r) {
        float v = acc[mi][ni][r] + bv;
        vv[r] = v;
        s += v;
        s2 += v * v;
      }
      if (tmpb) {
        unsigned d0 = f2bf(vv[0]) | ((unsigned)f2bf(vv[1]) << 16);
        unsigned d1 = f2bf(vv[2]) | ((unsigned)f2bf(vv[3]) << 16);
        *(uint2*)(tmpb + obase + mi * 16 + lg * 4) = make_uint2(d0, d1);
      } else {
        *(float4*)(outf + obase + mi * 16 + lg * 4) =
            make_float4(vv[0], vv[1], vv[2], vv[3]);
      }
    }
    s += __shfl_xor(s, 16);  s += __shfl_xor(s, 32);
    s2 += __shfl_xor(s2, 16); s2 += __shfl_xor(s2, 32);
    if (lg == 0) {
      sm[(wid * 4 + ni) * 32 + lc * 2] = s;
      sm[(wid * 4 + ni) * 32 + lc * 2 + 1] = s2;
    }
  }
  __syncthreads();
  if (tid < 128) {
    const int sel = tid >> 6, cc = tid & 63;
    const int ni = cc >> 4, lc2 = cc & 15;
    float r = 0.f;
#pragma unroll
    for (int w2 = 0; w2 < 4; ++w2) r += sm[(w2 * 4 + ni) * 32 + lc2 * 2 + sel];
    part[(size_t)wg * 128 + sel * 64 + cc] = r;
  }
}

// ---------------------------------------------------------------------------
// Finalize per-channel scale/shift from 512 block-partials.
// ---------------------------------------------------------------------------
__global__ __launch_bounds__(256) void stats_final_mf(
    const float* __restrict__ part, const float* __restrict__ gamma,
    const float* __restrict__ beta, float* __restrict__ ss) {
  const int c = blockIdx.x;  // 0..63
  const int tid = threadIdx.x;
  float s = 0.f, s2 = 0.f;
  for (int blk = tid; blk < 512; blk += 256) {
    s += part[(size_t)blk * 128 + c];
    s2 += part[(size_t)blk * 128 + 64 + c];
  }
#pragma unroll
  for (int off = 32; off; off >>= 1) {
    s += __shfl_down(s, off);
    s2 += __shfl_down(s2, off);
  }
  __shared__ float r0[4], r1[4];
  const int wid = tid >> 6, lane = tid & 63;
  if (lane == 0) { r0[wid] = s; r1[wid] = s2; }
  __syncthreads();
  if (tid == 0) {
    float S = r0[0] + r0[1] + r0[2] + r0[3];
    float S2 = r1[0] + r1[1] + r1[2] + r1[3];
    const float inv_n = 1.0f / 131072.f;
    float mean = S * inv_n;
    float var = S2 * inv_n - mean * mean;
    float inv = rsqrtf(var + EPS_);
    float sc = gamma[c] * inv;
    ss[c] = sc;
    ss[64 + c] = beta[c] - mean * sc;
  }
}

// ---------------------------------------------------------------------------
// BN apply + PReLU reading bf16 intermediate, writing fp32 out.
// ---------------------------------------------------------------------------
__global__ __launch_bounds__(256) void bn_prelu_b(
    const unsigned short* __restrict__ tmp, const float* __restrict__ ss,
    const float* __restrict__ alpha, float* __restrict__ out) {
  const float a = alpha[0];
  constexpr size_t N8 = (size_t)B_ * OUT_C_ * OUT_L_ * T_ / 8;  // 1,048,576
  for (size_t i = (size_t)blockIdx.x * 256 + threadIdx.x; i < N8;
       i += (size_t)gridDim.x * 256) {
    const int c = (int)((i >> 11) & 63);  // 2048 8-elem chunks per channel
    const float sc = ss[c];
    const float sh = ss[64 + c];
    ushort8 v = *(const ushort8*)(tmp + i * 8);
    float o[8];
#pragma unroll
    for (int r = 0; r < 8; ++r) {
      float f = __uint_as_float(((unsigned)v[r]) << 16) * sc + sh;
      o[r] = (f >= 0.f) ? f : a * f;
    }
    float4* op = (float4*)(out + i * 8);
    op[0] = make_float4(o[0], o[1], o[2], o[3]);
    op[1] = make_float4(o[4], o[5], o[6], o[7]);
  }
}

// ---------------------------------------------------------------------------
// BN apply + PReLU, fp32 in place (fallback when ws too small for tmp).
// ---------------------------------------------------------------------------
__global__ __launch_bounds__(256) void bn_prelu(
    float* __restrict__ out, const float* __restrict__ scaleshift,
    const float* __restrict__ alpha) {
  const float a = alpha[0];
  constexpr size_t N4 = (size_t)B_ * OUT_C_ * OUT_L_ * T_ / 4;
  float4* p = (float4*)out;
  for (size_t i = (size_t)blockIdx.x * 256 + threadIdx.x; i < N4;
       i += (size_t)gridDim.x * 256) {
    const int c = (int)((i >> 12) & 63);
    const float sc = scaleshift[c];
    const float sh = scaleshift[64 + c];
    float4 v = p[i];
    v.x = v.x * sc + sh; v.x = (v.x >= 0.f) ? v.x : a * v.x;
    v.y = v.y * sc + sh; v.y = (v.y >= 0.f) ? v.y : a * v.y;
    v.z = v.z * sc + sh; v.z = (v.z >= 0.f) ? v.z : a * v.z;
    v.w = v.w * sc + sh; v.w = (v.w >= 0.f) ? v.w : a * v.w;
    p[i] = v;
  }
}

extern "C" void kernel_launch(void* const* d_in, const int* in_sizes, int n_in,
                              void* d_out, int out_size, void* d_ws, size_t ws_size,
                              hipStream_t stream) {
  const float* x = (const float*)d_in[0];
  const float* w = (const float*)d_in[1];
  const float* bias = (const float*)d_in[2];
  const float* gamma = (const float*)d_in[3];
  const float* beta = (const float*)d_in[4];
  const float* alpha = (const float*)d_in[5];
  float* out = (float*)d_out;

  unsigned short* xT = (unsigned short*)d_ws;
  unsigned short* wT2 = (unsigned short*)((char*)d_ws + WT2_OFF_B);
  float* part = (float*)((char*)d_ws + PART_OFF_B);
  float* ssb = (float*)((char*)d_ws + SS_OFF_B);

  if (ws_size >= WS_NEED2) {
    unsigned short* tmpb = (unsigned short*)((char*)d_ws + TMP_OFF_B);
    prep_kernel<<<dim3(1176), dim3(256), 0, stream>>>(x, w, xT, wT2);
    conv_mfma<<<dim3(512), dim3(256), 0, stream>>>(xT, wT2, bias, out, tmpb, part);
    stats_final_mf<<<dim3(64), dim3(256), 0, stream>>>(part, gamma, beta, ssb);
    bn_prelu_b<<<dim3(2048), dim3(256), 0, stream>>>(tmpb, ssb, alpha, out);
  } else if (ws_size >= WS_NEED) {
    prep_kernel<<<dim3(1176), dim3(256), 0, stream>>>(x, w, xT, wT2);
    conv_mfma<<<dim3(512), dim3(256), 0, stream>>>(xT, wT2, bias, out, nullptr, part);
    stats_final_mf<<<dim3(64), dim3(256), 0, stream>>>(part, gamma, beta, ssb);
    bn_prelu<<<dim3(2048), dim3(256), 0, stream>>>(out, ssb, alpha);
  }
}

// Round 11
// 59.383 us; speedup vs baseline: 1.7196x; 1.4154x over previous
//
#include <hip/hip_runtime.h>

typedef __attribute__((ext_vector_type(8))) short short8;
typedef __attribute__((ext_vector_type(8))) unsigned short ushort8;
typedef __attribute__((ext_vector_type(4))) float f32x4;

// Problem constants
constexpr int B_ = 8, IN_C_ = 64, IN_L_ = 64, T_ = 256, OUT_C_ = 64, OUT_L_ = 64;
constexpr float EPS_ = 1e-5f;

// xT_pad: bf16 [8 b][66 lp][258 tp][64 ic]; lp = l+1, tp = t+1, halo rows/cols = 0
constexpr int XT_LP = 66, XT_TP = 258, XT_IC = 64;
constexpr int XT_LSTRIDE = XT_TP * XT_IC;            // 16512 elems
constexpr int XT_BSTRIDE = XT_LP * XT_LSTRIDE;       // 1,089,792 elems
constexpr size_t XT_ELEMS = (size_t)B_ * XT_BSTRIDE; // 8,718,336
constexpr size_t XT_BYTES = XT_ELEMS * 2;            // 17,436,672
// wT2: bf16 [64 l][9 tap][64 c][64 ic]
constexpr size_t WT2_ELEMS = 64ull * 9 * 64 * 64;    // 2,359,296
constexpr size_t WT2_OFF_B = XT_BYTES;
constexpr size_t PART_OFF_B = WT2_OFF_B + WT2_ELEMS * 2;   // 22,155,264
constexpr size_t SS_OFF_B = PART_OFF_B + 512ull * 128 * 4; // 22,417,408
constexpr size_t WS_NEED = SS_OFF_B + 128 * 4;             // 22,417,920
// bf16 intermediate (pre-BN conv output), 16.78 MB
constexpr size_t TMP_OFF_B = WS_NEED;
constexpr size_t TMP_BYTES = (size_t)B_ * OUT_C_ * OUT_L_ * T_ * 2;
constexpr size_t WS_NEED2 = TMP_OFF_B + TMP_BYTES;         // 39,195,136

__device__ __forceinline__ unsigned short f2bf(float f) {
  unsigned u = __float_as_uint(f);
  return (unsigned short)((u + 0x7fffu + ((u >> 16) & 1u)) >> 16);
}

__device__ __forceinline__ void gload_lds16(const void* g, void* l) {
  __builtin_amdgcn_global_load_lds(
      (const __attribute__((address_space(1))) unsigned int*)g,
      (__attribute__((address_space(3))) unsigned int*)l, 16, 0, 0);
}

// ---------------------------------------------------------------------------
// Prep (round-11 restructure): grid = 2184 blocks.
// Blocks [0,1152): wprep, FIRST so it overlaps xprep instead of tailing it.
//   8x wider than before: each thread handles 8 ic (8 strided loads, one
//   16B coalesced write) instead of 64 — kills the low-occupancy latency tail.
// Blocks [1152,2176): xprep — x fp32 [b][ic][l][t] -> xT bf16 [b][l+1][t+1][ic]
//   via LDS transpose (unchanged, streams at HBM).
// Blocks [2176,2184): zero xT halo (663 KB).
// ---------------------------------------------------------------------------
__global__ __launch_bounds__(256) void prep_kernel(const float* __restrict__ x,
                                                   const float* __restrict__ w,
                                                   unsigned short* __restrict__ xT,
                                                   unsigned short* __restrict__ wT2) {
  const int bid = blockIdx.x;
  const int tid = threadIdx.x;
  if (bid < 1152) {
    // g in [0, 294912): icg = g&7 (lane-fast -> 16B-coalesced writes),
    // c = (g>>3)&63, lt = g>>9 in [0,576)
    const int g = bid * 256 + tid;
    const int icg = g & 7;
    const int c = (g >> 3) & 63;
    const int lt = g >> 9;  // l*9 + tap
    const int l = lt / 9;
    const int tap = lt % 9;
    const float* src = w + ((size_t)tap * 64 + c) * 64 + l;  // + ic*36864
    unsigned d[4];
#pragma unroll
    for (int k = 0; k < 4; ++k) {
      float a = src[(size_t)(icg * 8 + 2 * k) * 36864];
      float c2 = src[(size_t)(icg * 8 + 2 * k + 1) * 36864];
      d[k] = f2bf(a) | ((unsigned)f2bf(c2) << 16);
    }
    *(uint4*)(wT2 + ((size_t)lt * 64 + c) * 64 + icg * 8) =
        make_uint4(d[0], d[1], d[2], d[3]);
  } else if (bid < 2176) {
    const int u = bid - 1152;
    const int th = u & 1, l = (u >> 1) & 63, b = u >> 7;
    const int t0 = th * 128;
    __shared__ unsigned short ls[64][132];  // [ic][t-local], pad keeps rows 8B-aligned
    {
      const int ic = tid >> 2, q = tid & 3;
      const float4* src = (const float4*)(x + (((size_t)(b * 64 + ic) * 64 + l) * 256 + t0));
#pragma unroll
      for (int e = 0; e < 8; ++e) {
        float4 v = src[q * 8 + e];
        const int toff = (q * 8 + e) * 4;
        unsigned d0 = f2bf(v.x) | ((unsigned)f2bf(v.y) << 16);
        unsigned d1 = f2bf(v.z) | ((unsigned)f2bf(v.w) << 16);
        *(uint2*)&ls[ic][toff] = make_uint2(d0, d1);
      }
    }
    __syncthreads();
    {
      const int tl = tid >> 1, h = tid & 1;  // t-row, ic-half
      unsigned d[16];
#pragma unroll
      for (int k = 0; k < 16; ++k) {
        unsigned short a = ls[h * 32 + 2 * k][tl];
        unsigned short c = ls[h * 32 + 2 * k + 1][tl];
        d[k] = a | ((unsigned)c << 16);
      }
      unsigned short* dst =
          xT + ((size_t)(b * XT_LP + l + 1) * XT_TP + (t0 + tl + 1)) * XT_IC + h * 32;
      uint4* dv = (uint4*)dst;
      dv[0] = make_uint4(d[0], d[1], d[2], d[3]);
      dv[1] = make_uint4(d[4], d[5], d[6], d[7]);
      dv[2] = make_uint4(d[8], d[9], d[10], d[11]);
      dv[3] = make_uint4(d[12], d[13], d[14], d[15]);
    }
  } else {
    const int b = bid - 2176;  // 0..7
    unsigned short* base = xT + (size_t)b * XT_BSTRIDE;
    const short8 z = {};
    // 16B chunks: 2 lp-planes (2*2064) + tp columns (66 lp * 2 cols * 8)
    for (int ci = tid; ci < 5184; ci += 256) {
      size_t off;
      if (ci < 4128) {
        const int plane = ci / 2064, k = ci % 2064;
        off = (size_t)(plane ? 65 : 0) * XT_LSTRIDE + (size_t)k * 8;
      } else {
        const int k = ci - 4128;            // 0..1055
        const int lp = k >> 4, rem = k & 15;
        const int tp = (rem < 8) ? 0 : 257;
        off = ((size_t)lp * XT_TP + tp) * 64 + (size_t)(rem & 7) * 8;
      }
      *(short8*)(base + off) = z;
    }
  }
}

// ---------------------------------------------------------------------------
// Main conv (EXACT round-8 kernel, proven): per (b,l) block, 256x64 GEMM over
// K=576 = 9 taps x 64. global_load_lds double-buffered staging with COUNTED
// vmcnt: per tap, {s_barrier; STAGE(next); vmcnt(10); sched_barrier;
// s_barrier; compute} — never draining to 0 in the main loop.
// XOR-swizzled LDS via pre-swizzled global source. Stores pre-BN bf16 to tmpb
// (or fp32 to outf). Fused per-channel sum/sumsq partials.
// ---------------------------------------------------------------------------
__global__ __launch_bounds__(256, 2) void conv_mfma(
    const unsigned short* __restrict__ xT, const unsigned short* __restrict__ wT2,
    const float* __restrict__ bias, float* __restrict__ outf,
    unsigned short* __restrict__ tmpb, float* __restrict__ part) {
  const int orig = blockIdx.x;                   // 0..511
  const int wg = (orig & 7) * 64 + (orig >> 3);  // XCD x -> batch b = x (L2 locality)
  const int b = wg >> 6, l = wg & 63;
  const int tid = threadIdx.x;
  const int wid = tid >> 6, ln = tid & 63;
  const int lc = ln & 15, lg = ln >> 4;
  const int m0 = wid * 64;

  // [buf][ A: 16384 elems (32 KB) | B: 4096 elems (8 KB) ] -> 80 KB total
  __shared__ unsigned short lds[2][20480];

  const int src_lane_off = ((ln >> 3) << 6) + ((((ln & 7) ^ (ln >> 3))) << 3);
  const unsigned short* xBase = xT + (size_t)(b * XT_LP + l) * XT_LSTRIDE + src_lane_off;
  const unsigned short* wBase = wT2 + (size_t)l * 9 * 4096 + src_lane_off;

  auto STAGE = [&](int buf, int tap) {
    const int i = tap / 3, j = tap - i * 3;
    const unsigned short* Ab = xBase + (size_t)i * XT_LSTRIDE + j * 64;
    unsigned short* La = &lds[buf][0];
#pragma unroll
    for (int q = 0; q < 8; ++q) {
      const int ch = wid * 8 + q;
      gload_lds16(Ab + ch * 512, La + ch * 512);
    }
    const unsigned short* Bb = wBase + (size_t)tap * 4096;
    unsigned short* Lb = &lds[buf][16384];
#pragma unroll
    for (int q = 0; q < 2; ++q) {
      const int ch = wid * 2 + q;
      gload_lds16(Bb + ch * 512, Lb + ch * 512);
    }
  };

  f32x4 acc[4][4] = {};

  STAGE(0, 0);
#pragma unroll
  for (int tap = 0; tap < 9; ++tap) {
    // barrier 1: all waves finished reading buf[(tap+1)&1] (in compute tap-1)
    __builtin_amdgcn_s_barrier();
    if (tap + 1 < 9) {
      STAGE((tap + 1) & 1, tap + 1);  // 10 gload_lds per wave into buf[(tap+1)&1]
      asm volatile("s_waitcnt vmcnt(10)" ::: "memory");
    } else {
      asm volatile("s_waitcnt vmcnt(0)" ::: "memory");
    }
    __builtin_amdgcn_sched_barrier(0);
    // barrier 2: every wave's stage(tap) contribution is now visible
    __builtin_amdgcn_s_barrier();
    __builtin_amdgcn_sched_barrier(0);

    const unsigned short* La = &lds[tap & 1][0];
    const unsigned short* Lb = &lds[tap & 1][16384];
#pragma unroll
    for (int kb = 0; kb < 2; ++kb) {
      const int slot = (((kb * 4 + lg) ^ (lc & 7)) << 3);
      short8 af[4], bf[4];
#pragma unroll
      for (int mi = 0; mi < 4; ++mi)
        af[mi] = *(const short8*)(La + (m0 + mi * 16 + lc) * 64 + slot);
#pragma unroll
      for (int ni = 0; ni < 4; ++ni)
        bf[ni] = *(const short8*)(Lb + (ni * 16 + lc) * 64 + slot);
#pragma unroll
      for (int mi = 0; mi < 4; ++mi)
#pragma unroll
        for (int ni = 0; ni < 4; ++ni)
          acc[mi][ni] =
              __builtin_amdgcn_mfma_f32_16x16x32_bf16(af[mi], bf[ni], acc[mi][ni], 0, 0, 0);
    }
  }

  // epilogue: bias + store (bf16 or fp32) + fused stats.
  __syncthreads();
  float* sm = (float*)&lds[0][0];  // sm[(wid*4+ni)*32 + lc*2 + sel]
#pragma unroll
  for (int ni = 0; ni < 4; ++ni) {
    const int c = ni * 16 + lc;
    const float bv = bias[c * 64 + l];
    float s = 0.f, s2 = 0.f;
    const size_t obase = ((size_t)(b * 64 + c) * 64 + l) * 256 + m0;
#pragma unroll
    for (int mi = 0; mi < 4; ++mi) {
      float vv[4];
#pragma unroll
      for (int r = 0; r < 4; ++r) {
        float v = acc[mi][ni][r] + bv;
        vv[r] = v;
        s += v;
        s2 += v * v;
      }
      if (tmpb) {
        unsigned d0 = f2bf(vv[0]) | ((unsigned)f2bf(vv[1]) << 16);
        unsigned d1 = f2bf(vv[2]) | ((unsigned)f2bf(vv[3]) << 16);
        *(uint2*)(tmpb + obase + mi * 16 + lg * 4) = make_uint2(d0, d1);
      } else {
        *(float4*)(outf + obase + mi * 16 + lg * 4) =
            make_float4(vv[0], vv[1], vv[2], vv[3]);
      }
    }
    s += __shfl_xor(s, 16);  s += __shfl_xor(s, 32);
    s2 += __shfl_xor(s2, 16); s2 += __shfl_xor(s2, 32);
    if (lg == 0) {
      sm[(wid * 4 + ni) * 32 + lc * 2] = s;
      sm[(wid * 4 + ni) * 32 + lc * 2 + 1] = s2;
    }
  }
  __syncthreads();
  if (tid < 128) {
    const int sel = tid >> 6, cc = tid & 63;
    const int ni = cc >> 4, lc2 = cc & 15;
    float r = 0.f;
#pragma unroll
    for (int w2 = 0; w2 < 4; ++w2) r += sm[(w2 * 4 + ni) * 32 + lc2 * 2 + sel];
    part[(size_t)wg * 128 + sel * 64 + cc] = r;
  }
}

// ---------------------------------------------------------------------------
// Finalize per-channel scale/shift from 512 block-partials.
// ---------------------------------------------------------------------------
__global__ __launch_bounds__(256) void stats_final_mf(
    const float* __restrict__ part, const float* __restrict__ gamma,
    const float* __restrict__ beta, float* __restrict__ ss) {
  const int c = blockIdx.x;  // 0..63
  const int tid = threadIdx.x;
  float s = 0.f, s2 = 0.f;
  for (int blk = tid; blk < 512; blk += 256) {
    s += part[(size_t)blk * 128 + c];
    s2 += part[(size_t)blk * 128 + 64 + c];
  }
#pragma unroll
  for (int off = 32; off; off >>= 1) {
    s += __shfl_down(s, off);
    s2 += __shfl_down(s2, off);
  }
  __shared__ float r0[4], r1[4];
  const int wid = tid >> 6, lane = tid & 63;
  if (lane == 0) { r0[wid] = s; r1[wid] = s2; }
  __syncthreads();
  if (tid == 0) {
    float S = r0[0] + r0[1] + r0[2] + r0[3];
    float S2 = r1[0] + r1[1] + r1[2] + r1[3];
    const float inv_n = 1.0f / 131072.f;
    float mean = S * inv_n;
    float var = S2 * inv_n - mean * mean;
    float inv = rsqrtf(var + EPS_);
    float sc = gamma[c] * inv;
    ss[c] = sc;
    ss[64 + c] = beta[c] - mean * sc;
  }
}

// ---------------------------------------------------------------------------
// BN apply + PReLU reading bf16 intermediate, writing fp32 out.
// ---------------------------------------------------------------------------
__global__ __launch_bounds__(256) void bn_prelu_b(
    const unsigned short* __restrict__ tmp, const float* __restrict__ ss,
    const float* __restrict__ alpha, float* __restrict__ out) {
  const float a = alpha[0];
  constexpr size_t N8 = (size_t)B_ * OUT_C_ * OUT_L_ * T_ / 8;  // 1,048,576
  for (size_t i = (size_t)blockIdx.x * 256 + threadIdx.x; i < N8;
       i += (size_t)gridDim.x * 256) {
    const int c = (int)((i >> 11) & 63);  // 2048 8-elem chunks per channel
    const float sc = ss[c];
    const float sh = ss[64 + c];
    ushort8 v = *(const ushort8*)(tmp + i * 8);
    float o[8];
#pragma unroll
    for (int r = 0; r < 8; ++r) {
      float f = __uint_as_float(((unsigned)v[r]) << 16) * sc + sh;
      o[r] = (f >= 0.f) ? f : a * f;
    }
    float4* op = (float4*)(out + i * 8);
    op[0] = make_float4(o[0], o[1], o[2], o[3]);
    op[1] = make_float4(o[4], o[5], o[6], o[7]);
  }
}

// ---------------------------------------------------------------------------
// BN apply + PReLU, fp32 in place (fallback when ws too small for tmp).
// ---------------------------------------------------------------------------
__global__ __launch_bounds__(256) void bn_prelu(
    float* __restrict__ out, const float* __restrict__ scaleshift,
    const float* __restrict__ alpha) {
  const float a = alpha[0];
  constexpr size_t N4 = (size_t)B_ * OUT_C_ * OUT_L_ * T_ / 4;
  float4* p = (float4*)out;
  for (size_t i = (size_t)blockIdx.x * 256 + threadIdx.x; i < N4;
       i += (size_t)gridDim.x * 256) {
    const int c = (int)((i >> 12) & 63);
    const float sc = scaleshift[c];
    const float sh = scaleshift[64 + c];
    float4 v = p[i];
    v.x = v.x * sc + sh; v.x = (v.x >= 0.f) ? v.x : a * v.x;
    v.y = v.y * sc + sh; v.y = (v.y >= 0.f) ? v.y : a * v.y;
    v.z = v.z * sc + sh; v.z = (v.z >= 0.f) ? v.z : a * v.z;
    v.w = v.w * sc + sh; v.w = (v.w >= 0.f) ? v.w : a * v.w;
    p[i] = v;
  }
}

extern "C" void kernel_launch(void* const* d_in, const int* in_sizes, int n_in,
                              void* d_out, int out_size, void* d_ws, size_t ws_size,
                              hipStream_t stream) {
  const float* x = (const float*)d_in[0];
  const float* w = (const float*)d_in[1];
  const float* bias = (const float*)d_in[2];
  const float* gamma = (const float*)d_in[3];
  const float* beta = (const float*)d_in[4];
  const float* alpha = (const float*)d_in[5];
  float* out = (float*)d_out;

  unsigned short* xT = (unsigned short*)d_ws;
  unsigned short* wT2 = (unsigned short*)((char*)d_ws + WT2_OFF_B);
  float* part = (float*)((char*)d_ws + PART_OFF_B);
  float* ssb = (float*)((char*)d_ws + SS_OFF_B);

  if (ws_size >= WS_NEED2) {
    unsigned short* tmpb = (unsigned short*)((char*)d_ws + TMP_OFF_B);
    prep_kernel<<<dim3(2184), dim3(256), 0, stream>>>(x, w, xT, wT2);
    conv_mfma<<<dim3(512), dim3(256), 0, stream>>>(xT, wT2, bias, out, tmpb, part);
    stats_final_mf<<<dim3(64), dim3(256), 0, stream>>>(part, gamma, beta, ssb);
    bn_prelu_b<<<dim3(2048), dim3(256), 0, stream>>>(tmpb, ssb, alpha, out);
  } else if (ws_size >= WS_NEED) {
    prep_kernel<<<dim3(2184), dim3(256), 0, stream>>>(x, w, xT, wT2);
    conv_mfma<<<dim3(512), dim3(256), 0, stream>>>(xT, wT2, bias, out, nullptr, part);
    stats_final_mf<<<dim3(64), dim3(256), 0, stream>>>(part, gamma, beta, ssb);
    bn_prelu<<<dim3(2048), dim3(256), 0, stream>>>(out, ssb, alpha);
  }
}

// Round 12
// 51.689 us; speedup vs baseline: 1.9756x; 1.1488x over previous
//
#include <hip/hip_runtime.h>

typedef __attribute__((ext_vector_type(8))) short short8;
typedef __attribute__((ext_vector_type(8))) unsigned short ushort8;
typedef __attribute__((ext_vector_type(4))) float f32x4;

// Problem constants
constexpr int B_ = 8, IN_C_ = 64, IN_L_ = 64, T_ = 256, OUT_C_ = 64, OUT_L_ = 64;
constexpr float EPS_ = 1e-5f;

// xT_pad: bf16 [8 b][66 lp][258 tp][64 ic]; lp = l+1, tp = t+1, halo rows/cols = 0
constexpr int XT_LP = 66, XT_TP = 258, XT_IC = 64;
constexpr int XT_LSTRIDE = XT_TP * XT_IC;            // 16512 elems
constexpr int XT_BSTRIDE = XT_LP * XT_LSTRIDE;       // 1,089,792 elems
constexpr size_t XT_ELEMS = (size_t)B_ * XT_BSTRIDE; // 8,718,336
constexpr size_t XT_BYTES = XT_ELEMS * 2;            // 17,436,672
// wT2: bf16 [64 l][9 tap][64 c][64 ic]
constexpr size_t WT2_ELEMS = 64ull * 9 * 64 * 64;    // 2,359,296
constexpr size_t WT2_OFF_B = XT_BYTES;
constexpr size_t PART_OFF_B = WT2_OFF_B + WT2_ELEMS * 2;   // 22,155,264
constexpr size_t SS_OFF_B = PART_OFF_B + 512ull * 128 * 4; // 22,417,408
constexpr size_t WS_NEED = SS_OFF_B + 128 * 4;             // 22,417,920
// bf16 intermediate (pre-BN conv output), 16.78 MB
constexpr size_t TMP_OFF_B = WS_NEED;
constexpr size_t TMP_BYTES = (size_t)B_ * OUT_C_ * OUT_L_ * T_ * 2;
constexpr size_t WS_NEED2 = TMP_OFF_B + TMP_BYTES;         // 39,195,136

__device__ __forceinline__ unsigned short f2bf(float f) {
  unsigned u = __float_as_uint(f);
  return (unsigned short)((u + 0x7fffu + ((u >> 16) & 1u)) >> 16);
}

__device__ __forceinline__ void gload_lds16(const void* g, void* l) {
  __builtin_amdgcn_global_load_lds(
      (const __attribute__((address_space(1))) unsigned int*)g,
      (__attribute__((address_space(3))) unsigned int*)l, 16, 0, 0);
}

// ---------------------------------------------------------------------------
// Prep (round-12): grid = 1176 blocks, one shared LDS buffer (34.8 KB).
// Blocks [0,144): wprep as a COALESCED LDS TRANSPOSE. Block = (tap, c-group
//   of 4). Thread (ic, cl) streams one full w row (64 contiguous floats =
//   w[ic*9+tap][c0+cl][0..63]), converts to bf16 into wls[l][cl][ic]; then
//   thread (l, cl) writes the contiguous 128 B chunk wT2[l][tap][c0+cl][*].
//   Replaces the old 147 KB-stride scatter reads (latency tail).
// Blocks [144,1168): xprep — x fp32 [b][ic][l][t] -> xT bf16 [b][l+1][t+1][ic]
//   via LDS transpose (unchanged).
// Blocks [1168,1176): zero xT halo (663 KB).
// ---------------------------------------------------------------------------
__global__ __launch_bounds__(256) void prep_kernel(const float* __restrict__ x,
                                                   const float* __restrict__ w,
                                                   unsigned short* __restrict__ xT,
                                                   unsigned short* __restrict__ wT2) {
  const int bid = blockIdx.x;
  const int tid = threadIdx.x;
  __shared__ unsigned char shmem[34816];
  if (bid < 144) {
    // wprep transpose: tap = bid/16, c0 = (bid&15)*4
    const int tap = bid >> 4;
    const int c0 = (bid & 15) * 4;
    auto wls = (unsigned short(*)[4][68])shmem;  // [l][cl][ic] (pad 68)
    {
      const int ic = tid >> 2, cl = tid & 3;
      const float* src = w + (((size_t)(ic * 9 + tap) * 64) + (c0 + cl)) * 64;
#pragma unroll
      for (int e = 0; e < 16; ++e) {
        float4 v = ((const float4*)src)[e];
        const int l = e * 4;
        wls[l + 0][cl][ic] = f2bf(v.x);
        wls[l + 1][cl][ic] = f2bf(v.y);
        wls[l + 2][cl][ic] = f2bf(v.z);
        wls[l + 3][cl][ic] = f2bf(v.w);
      }
    }
    __syncthreads();
    {
      const int l = tid >> 2, cl = tid & 3;
      const unsigned short* row = &wls[l][cl][0];
      uint4* dst = (uint4*)(wT2 + ((size_t)(l * 9 + tap)) * 4096 + (c0 + cl) * 64);
#pragma unroll
      for (int q = 0; q < 8; ++q) dst[q] = ((const uint4*)row)[q];
    }
  } else if (bid < 1168) {
    const int u = bid - 144;
    const int th = u & 1, l = (u >> 1) & 63, b = u >> 7;
    const int t0 = th * 128;
    auto ls = (unsigned short(*)[132])shmem;  // [ic][t-local], 16.9 KB
    {
      const int ic = tid >> 2, q = tid & 3;
      const float4* src = (const float4*)(x + (((size_t)(b * 64 + ic) * 64 + l) * 256 + t0));
#pragma unroll
      for (int e = 0; e < 8; ++e) {
        float4 v = src[q * 8 + e];
        const int toff = (q * 8 + e) * 4;
        unsigned d0 = f2bf(v.x) | ((unsigned)f2bf(v.y) << 16);
        unsigned d1 = f2bf(v.z) | ((unsigned)f2bf(v.w) << 16);
        *(uint2*)&ls[ic][toff] = make_uint2(d0, d1);
      }
    }
    __syncthreads();
    {
      const int tl = tid >> 1, h = tid & 1;  // t-row, ic-half
      unsigned d[16];
#pragma unroll
      for (int k = 0; k < 16; ++k) {
        unsigned short a = ls[h * 32 + 2 * k][tl];
        unsigned short c = ls[h * 32 + 2 * k + 1][tl];
        d[k] = a | ((unsigned)c << 16);
      }
      unsigned short* dst =
          xT + ((size_t)(b * XT_LP + l + 1) * XT_TP + (t0 + tl + 1)) * XT_IC + h * 32;
      uint4* dv = (uint4*)dst;
      dv[0] = make_uint4(d[0], d[1], d[2], d[3]);
      dv[1] = make_uint4(d[4], d[5], d[6], d[7]);
      dv[2] = make_uint4(d[8], d[9], d[10], d[11]);
      dv[3] = make_uint4(d[12], d[13], d[14], d[15]);
    }
  } else {
    const int b = bid - 1168;  // 0..7
    unsigned short* base = xT + (size_t)b * XT_BSTRIDE;
    const short8 z = {};
    // 16B chunks: 2 lp-planes (2*2064) + tp columns (66 lp * 2 cols * 8)
    for (int ci = tid; ci < 5184; ci += 256) {
      size_t off;
      if (ci < 4128) {
        const int plane = ci / 2064, k = ci % 2064;
        off = (size_t)(plane ? 65 : 0) * XT_LSTRIDE + (size_t)k * 8;
      } else {
        const int k = ci - 4128;            // 0..1055
        const int lp = k >> 4, rem = k & 15;
        const int tp = (rem < 8) ? 0 : 257;
        off = ((size_t)lp * XT_TP + tp) * 64 + (size_t)(rem & 7) * 8;
      }
      *(short8*)(base + off) = z;
    }
  }
}

// ---------------------------------------------------------------------------
// Main conv (r8 structure, proven; r12 change = l-major XCD swizzle): per
// (b,l) block, 256x64 GEMM over K=576 = 9 taps x 64. global_load_lds
// double-buffered staging with COUNTED vmcnt: per tap, {s_barrier;
// STAGE(next); vmcnt(10); sched_barrier; s_barrier; compute}. XOR-swizzled
// LDS via pre-swizzled global source. l-major swizzle: XCD k owns l in
// [8k,8k+8) for all b -> per-XCD set = wT2 590 KB + xT 2.6 MB (L2-resident).
// ---------------------------------------------------------------------------
__global__ __launch_bounds__(256, 2) void conv_mfma(
    const unsigned short* __restrict__ xT, const unsigned short* __restrict__ wT2,
    const float* __restrict__ bias, float* __restrict__ outf,
    unsigned short* __restrict__ tmpb, float* __restrict__ part) {
  const int orig = blockIdx.x;  // 0..511
  // l-major XCD swizzle: b = orig>>6, l = (orig&7)*8 + ((orig>>3)&7)
  const int wg = (orig >> 6) * 64 + (orig & 7) * 8 + ((orig >> 3) & 7);
  const int b = wg >> 6, l = wg & 63;
  const int tid = threadIdx.x;
  const int wid = tid >> 6, ln = tid & 63;
  const int lc = ln & 15, lg = ln >> 4;
  const int m0 = wid * 64;

  // [buf][ A: 16384 elems (32 KB) | B: 4096 elems (8 KB) ] -> 80 KB total
  __shared__ unsigned short lds[2][20480];

  const int src_lane_off = ((ln >> 3) << 6) + ((((ln & 7) ^ (ln >> 3))) << 3);
  const unsigned short* xBase = xT + (size_t)(b * XT_LP + l) * XT_LSTRIDE + src_lane_off;
  const unsigned short* wBase = wT2 + (size_t)l * 9 * 4096 + src_lane_off;

  auto STAGE = [&](int buf, int tap) {
    const int i = tap / 3, j = tap - i * 3;
    const unsigned short* Ab = xBase + (size_t)i * XT_LSTRIDE + j * 64;
    unsigned short* La = &lds[buf][0];
#pragma unroll
    for (int q = 0; q < 8; ++q) {
      const int ch = wid * 8 + q;
      gload_lds16(Ab + ch * 512, La + ch * 512);
    }
    const unsigned short* Bb = wBase + (size_t)tap * 4096;
    unsigned short* Lb = &lds[buf][16384];
#pragma unroll
    for (int q = 0; q < 2; ++q) {
      const int ch = wid * 2 + q;
      gload_lds16(Bb + ch * 512, Lb + ch * 512);
    }
  };

  f32x4 acc[4][4] = {};

  STAGE(0, 0);
#pragma unroll
  for (int tap = 0; tap < 9; ++tap) {
    // barrier 1: all waves finished reading buf[(tap+1)&1] (in compute tap-1)
    __builtin_amdgcn_s_barrier();
    if (tap + 1 < 9) {
      STAGE((tap + 1) & 1, tap + 1);  // 10 gload_lds per wave into buf[(tap+1)&1]
      asm volatile("s_waitcnt vmcnt(10)" ::: "memory");
    } else {
      asm volatile("s_waitcnt vmcnt(0)" ::: "memory");
    }
    __builtin_amdgcn_sched_barrier(0);
    // barrier 2: every wave's stage(tap) contribution is now visible
    __builtin_amdgcn_s_barrier();
    __builtin_amdgcn_sched_barrier(0);

    const unsigned short* La = &lds[tap & 1][0];
    const unsigned short* Lb = &lds[tap & 1][16384];
#pragma unroll
    for (int kb = 0; kb < 2; ++kb) {
      const int slot = (((kb * 4 + lg) ^ (lc & 7)) << 3);
      short8 af[4], bf[4];
#pragma unroll
      for (int mi = 0; mi < 4; ++mi)
        af[mi] = *(const short8*)(La + (m0 + mi * 16 + lc) * 64 + slot);
#pragma unroll
      for (int ni = 0; ni < 4; ++ni)
        bf[ni] = *(const short8*)(Lb + (ni * 16 + lc) * 64 + slot);
#pragma unroll
      for (int mi = 0; mi < 4; ++mi)
#pragma unroll
        for (int ni = 0; ni < 4; ++ni)
          acc[mi][ni] =
              __builtin_amdgcn_mfma_f32_16x16x32_bf16(af[mi], bf[ni], acc[mi][ni], 0, 0, 0);
    }
  }

  // epilogue: bias + store (bf16 or fp32) + fused stats.
  __syncthreads();
  float* sm = (float*)&lds[0][0];  // sm[(wid*4+ni)*32 + lc*2 + sel]
#pragma unroll
  for (int ni = 0; ni < 4; ++ni) {
    const int c = ni * 16 + lc;
    const float bv = bias[c * 64 + l];
    float s = 0.f, s2 = 0.f;
    const size_t obase = ((size_t)(b * 64 + c) * 64 + l) * 256 + m0;
#pragma unroll
    for (int mi = 0; mi < 4; ++mi) {
      float vv[4];
#pragma unroll
      for (int r = 0; r < 4; ++r) {
        float v = acc[mi][ni][r] + bv;
        vv[r] = v;
        s += v;
        s2 += v * v;
      }
      if (tmpb) {
        unsigned d0 = f2bf(vv[0]) | ((unsigned)f2bf(vv[1]) << 16);
        unsigned d1 = f2bf(vv[2]) | ((unsigned)f2bf(vv[3]) << 16);
        *(uint2*)(tmpb + obase + mi * 16 + lg * 4) = make_uint2(d0, d1);
      } else {
        *(float4*)(outf + obase + mi * 16 + lg * 4) =
            make_float4(vv[0], vv[1], vv[2], vv[3]);
      }
    }
    s += __shfl_xor(s, 16);  s += __shfl_xor(s, 32);
    s2 += __shfl_xor(s2, 16); s2 += __shfl_xor(s2, 32);
    if (lg == 0) {
      sm[(wid * 4 + ni) * 32 + lc * 2] = s;
      sm[(wid * 4 + ni) * 32 + lc * 2 + 1] = s2;
    }
  }
  __syncthreads();
  if (tid < 128) {
    const int sel = tid >> 6, cc = tid & 63;
    const int ni = cc >> 4, lc2 = cc & 15;
    float r = 0.f;
#pragma unroll
    for (int w2 = 0; w2 < 4; ++w2) r += sm[(w2 * 4 + ni) * 32 + lc2 * 2 + sel];
    part[(size_t)wg * 128 + sel * 64 + cc] = r;
  }
}

// ---------------------------------------------------------------------------
// Finalize per-channel scale/shift from 512 block-partials.
// ---------------------------------------------------------------------------
__global__ __launch_bounds__(256) void stats_final_mf(
    const float* __restrict__ part, const float* __restrict__ gamma,
    const float* __restrict__ beta, float* __restrict__ ss) {
  const int c = blockIdx.x;  // 0..63
  const int tid = threadIdx.x;
  float s = 0.f, s2 = 0.f;
  for (int blk = tid; blk < 512; blk += 256) {
    s += part[(size_t)blk * 128 + c];
    s2 += part[(size_t)blk * 128 + 64 + c];
  }
#pragma unroll
  for (int off = 32; off; off >>= 1) {
    s += __shfl_down(s, off);
    s2 += __shfl_down(s2, off);
  }
  __shared__ float r0[4], r1[4];
  const int wid = tid >> 6, lane = tid & 63;
  if (lane == 0) { r0[wid] = s; r1[wid] = s2; }
  __syncthreads();
  if (tid == 0) {
    float S = r0[0] + r0[1] + r0[2] + r0[3];
    float S2 = r1[0] + r1[1] + r1[2] + r1[3];
    const float inv_n = 1.0f / 131072.f;
    float mean = S * inv_n;
    float var = S2 * inv_n - mean * mean;
    float inv = rsqrtf(var + EPS_);
    float sc = gamma[c] * inv;
    ss[c] = sc;
    ss[64 + c] = beta[c] - mean * sc;
  }
}

// ---------------------------------------------------------------------------
// BN apply + PReLU reading bf16 intermediate, writing fp32 out.
// ---------------------------------------------------------------------------
__global__ __launch_bounds__(256) void bn_prelu_b(
    const unsigned short* __restrict__ tmp, const float* __restrict__ ss,
    const float* __restrict__ alpha, float* __restrict__ out) {
  const float a = alpha[0];
  constexpr size_t N8 = (size_t)B_ * OUT_C_ * OUT_L_ * T_ / 8;  // 1,048,576
  for (size_t i = (size_t)blockIdx.x * 256 + threadIdx.x; i < N8;
       i += (size_t)gridDim.x * 256) {
    const int c = (int)((i >> 11) & 63);  // 2048 8-elem chunks per channel
    const float sc = ss[c];
    const float sh = ss[64 + c];
    ushort8 v = *(const ushort8*)(tmp + i * 8);
    float o[8];
#pragma unroll
    for (int r = 0; r < 8; ++r) {
      float f = __uint_as_float(((unsigned)v[r]) << 16) * sc + sh;
      o[r] = (f >= 0.f) ? f : a * f;
    }
    float4* op = (float4*)(out + i * 8);
    op[0] = make_float4(o[0], o[1], o[2], o[3]);
    op[1] = make_float4(o[4], o[5], o[6], o[7]);
  }
}

// ---------------------------------------------------------------------------
// BN apply + PReLU, fp32 in place (fallback when ws too small for tmp).
// ---------------------------------------------------------------------------
__global__ __launch_bounds__(256) void bn_prelu(
    float* __restrict__ out, const float* __restrict__ scaleshift,
    const float* __restrict__ alpha) {
  const float a = alpha[0];
  constexpr size_t N4 = (size_t)B_ * OUT_C_ * OUT_L_ * T_ / 4;
  float4* p = (float4*)out;
  for (size_t i = (size_t)blockIdx.x * 256 + threadIdx.x; i < N4;
       i += (size_t)gridDim.x * 256) {
    const int c = (int)((i >> 12) & 63);
    const float sc = scaleshift[c];
    const float sh = scaleshift[64 + c];
    float4 v = p[i];
    v.x = v.x * sc + sh; v.x = (v.x >= 0.f) ? v.x : a * v.x;
    v.y = v.y * sc + sh; v.y = (v.y >= 0.f) ? v.y : a * v.y;
    v.z = v.z * sc + sh; v.z = (v.z >= 0.f) ? v.z : a * v.z;
    v.w = v.w * sc + sh; v.w = (v.w >= 0.f) ? v.w : a * v.w;
    p[i] = v;
  }
}

extern "C" void kernel_launch(void* const* d_in, const int* in_sizes, int n_in,
                              void* d_out, int out_size, void* d_ws, size_t ws_size,
                              hipStream_t stream) {
  const float* x = (const float*)d_in[0];
  const float* w = (const float*)d_in[1];
  const float* bias = (const float*)d_in[2];
  const float* gamma = (const float*)d_in[3];
  const float* beta = (const float*)d_in[4];
  const float* alpha = (const float*)d_in[5];
  float* out = (float*)d_out;

  unsigned short* xT = (unsigned short*)d_ws;
  unsigned short* wT2 = (unsigned short*)((char*)d_ws + WT2_OFF_B);
  float* part = (float*)((char*)d_ws + PART_OFF_B);
  float* ssb = (float*)((char*)d_ws + SS_OFF_B);

  if (ws_size >= WS_NEED2) {
    unsigned short* tmpb = (unsigned short*)((char*)d_ws + TMP_OFF_B);
    prep_kernel<<<dim3(1176), dim3(256), 0, stream>>>(x, w, xT, wT2);
    conv_mfma<<<dim3(512), dim3(256), 0, stream>>>(xT, wT2, bias, out, tmpb, part);
    stats_final_mf<<<dim3(64), dim3(256), 0, stream>>>(part, gamma, beta, ssb);
    bn_prelu_b<<<dim3(2048), dim3(256), 0, stream>>>(tmpb, ssb, alpha, out);
  } else if (ws_size >= WS_NEED) {
    prep_kernel<<<dim3(1176), dim3(256), 0, stream>>>(x, w, xT, wT2);
    conv_mfma<<<dim3(512), dim3(256), 0, stream>>>(xT, wT2, bias, out, nullptr, part);
    stats_final_mf<<<dim3(64), dim3(256), 0, stream>>>(part, gamma, beta, ssb);
    bn_prelu<<<dim3(2048), dim3(256), 0, stream>>>(out, ssb, alpha);
  }
}